// Round 10
// baseline (151.510 us; speedup 1.0000x reference)
//
#include <hip/hip_runtime.h>

// Causal GQA attention prefill, fp32 in/out, MFMA 32x32x16 bf16 compute.
// S=2048, H=32, KVH=8 (rep=4), D=128.
// Round 15: DE-LOCKSTEP. Rounds 12-14 proved the binder is neither bank
// conflicts, nor addr VALU, nor softmax VALU, nor in-wave ILP: per-iteration
// time (10.2k cyc) is ~2x the fully-serialized resource demand, because all
// 8 waves were phase-locked by two block-wide barriers at 2 waves/SIMD --
// a stalled wave's SIMD-partner is at the same point of the same schedule.
// This round restores TLP:
//   1) 256-thread blocks (4 waves = 4 q-subtiles; each wave owns the FULL
//      key range), BK=64, K/V double-buffered = 64 KB LDS -> TWO independent
//      blocks per CU with uncorrelated barrier schedules. When block A
//      stalls, block B's waves fill the SIMD.
//   2) No key-group split -> epilogue merge (obuf/Sl + 3 syncthreads) gone;
//      each wave normalizes with its own lacc and stores directly.
//   3) Uniform work: blocks i and i+256 (same CU slot, same XCD) take
//      q-tiles px and 15-px -> 34 BK=64 iterations per CU.
// Kept: slice-major workspaces (re-cut to 64-key tiles; zero conflicts,
// immediate-offset ds_reads), unnormalized softmax (exp2 direct, log2-domain
// QK with SCALE*log2e folded into Q), ones-MFMA row-sum, gload_lds width-16
// linear staging, counted-vmcnt depth-2 pipeline, XCD-exact h mapping.

#define SEQ   2048
#define NH    32
#define NKVH  8
#define HD    128
#define BQ    128
#define KSS   136    // fallback kernel K stride
#define VTSF  72     // fallback kernel V stride
#define PSS   72     // fallback ps stride
#define SCALE 0.08838834764831845f
#define QS    (0.08838834764831845f * 1.4426950408889634f)   // SCALE * log2(e)

#define T64_SH   8192                        // shorts per 64-key tile (16 KB)
#define KB_ELEMS (SEQ * NKVH * HD)           // 2,097,152 ushorts
#define WS_NEED  (2u * KB_ELEMS * 2u)        // kws + vws, bytes

typedef __attribute__((ext_vector_type(8)))  short short8;
typedef __attribute__((ext_vector_type(16))) float float16;
typedef __attribute__((ext_vector_type(2)))  unsigned int uint2v;

__device__ __forceinline__ unsigned short f2bf(float f) {
    union { float f; unsigned int i; } x; x.f = f;
    unsigned int r = x.i + 0x7fffu + ((x.i >> 16) & 1u);   // RNE
    return (unsigned short)(r >> 16);
}
__device__ __forceinline__ unsigned int f2bf2(float lo, float hi) {
    return (unsigned int)f2bf(lo) | ((unsigned int)f2bf(hi) << 16);
}
__device__ __forceinline__ unsigned int cvt_pk_bf16(float lo, float hi) {
    unsigned int r;
    asm("v_cvt_pk_bf16_f32 %0, %1, %2" : "=v"(r) : "v"(lo), "v"(hi));
    return r;
}

// direct global->LDS copy, 16 B per lane; LDS dest is wave-uniform base,
// HW adds lane*16; global src is per-lane.
__device__ __forceinline__ void gload_lds16(const unsigned short* g, unsigned short* l) {
    __builtin_amdgcn_global_load_lds(
        (const __attribute__((address_space(1))) void*)g,
        (__attribute__((address_space(3))) void*)l, 16, 0, 0);
}

#if __has_builtin(__builtin_amdgcn_permlane32_swap)
#define PLSWAP(a, b, xout, yout) do { \
    uint2v r_ = __builtin_amdgcn_permlane32_swap((a), (b), false, false); \
    (xout) = r_.x; (yout) = r_.y; } while (0)
#else
#define PLSWAP(a, b, xout, yout) do { \
    unsigned int a_ = (a), b_ = (b); \
    asm volatile("s_nop 1\n\tv_permlane32_swap_b32 %0, %1" : "+v"(a_), "+v"(b_)); \
    (xout) = a_; (yout) = b_; } while (0)
#endif

#define MAKE_AF(dst, sv, b) do { \
    const unsigned int p0_ = cvt_pk_bf16(sv[(b) + 0], sv[(b) + 1]); \
    const unsigned int p1_ = cvt_pk_bf16(sv[(b) + 2], sv[(b) + 3]); \
    const unsigned int p2_ = cvt_pk_bf16(sv[(b) + 4], sv[(b) + 5]); \
    const unsigned int p3_ = cvt_pk_bf16(sv[(b) + 6], sv[(b) + 7]); \
    unsigned int w0_, w1_, w2_, w3_; \
    PLSWAP(p0_, p2_, w0_, w2_); \
    PLSWAP(p1_, p3_, w1_, w3_); \
    union { short8 v; unsigned int u[4]; } uu_; \
    uu_.u[0] = w0_; uu_.u[1] = w1_; uu_.u[2] = w2_; uu_.u[3] = w3_; \
    (dst) = uu_.v; } while (0)

// ---- prep: slice-major bf16 workspaces in 64-key tiles ----
// kws[kvh][t64:32][gl16][row64] : unit (gl*64+row)*8 holds
//   K[t64*64+row][d = gl*8 .. +8) as bf16.
// vws[kvh][t64:32][gl8][d128]   : unit (gl*128+d)*8 holds
//   V[key = t64*64+gl*8+e][d], e=0..7 (V^T key-slice at dim d).
__global__ __launch_bounds__(256)
void cvt_kv4(const float* __restrict__ k, const float* __restrict__ v,
             unsigned short* __restrict__ kws, unsigned short* __restrict__ vws)
{
    __shared__ unsigned short tl[128 * 144];
    const int t = threadIdx.x;
    if (blockIdx.x < 128) {                  // ---- K ----
        const int bid  = blockIdx.x;
        const int kvh  = bid >> 4, t128 = bid & 15;
        unsigned short* dst = kws + ((size_t)(kvh * 32) + t128 * 2) * T64_SH;
        #pragma unroll
        for (int rr = 0; rr < 8; ++rr) {
            const int gid = rr * 256 + t;    // 0..2047
            const int gl = gid >> 7, row = gid & 127;
            const float* src =
                k + ((size_t)(t128 * 128 + row) * NKVH + kvh) * HD + gl * 8;
            const float4 a = *(const float4*)(src);
            const float4 b = *(const float4*)(src + 4);
            uint4 o;
            o.x = f2bf2(a.x, a.y); o.y = f2bf2(a.z, a.w);
            o.z = f2bf2(b.x, b.y); o.w = f2bf2(b.z, b.w);
            const size_t off = (size_t)(row >> 6) * T64_SH + (gl * 64 + (row & 63)) * 8;
            *(uint4*)(dst + off) = o;
        }
        return;
    }
    // ---- V transpose + slice-major ----
    const int bid  = blockIdx.x - 128;
    const int kvh  = bid >> 4, t128 = bid & 15;
    const int dp   = (t & 63) * 2;
    const int k0q  = t >> 6;
    #pragma unroll
    for (int rr = 0; rr < 32; ++rr) {
        const int key = k0q + rr * 4;        // 0..127
        const float2 a =
            *(const float2*)(v + ((size_t)(t128 * 128 + key) * NKVH + kvh) * HD + dp);
        tl[dp * 144 + key]       = f2bf(a.x);
        tl[(dp + 1) * 144 + key] = f2bf(a.y);
    }
    __syncthreads();
    unsigned short* dst = vws + ((size_t)(kvh * 32) + t128 * 2) * T64_SH;
    #pragma unroll
    for (int rr = 0; rr < 8; ++rr) {
        const int gid = rr * 256 + t;
        const int d = gid & 127, gk = gid >> 7;      // gk: key-granule 0..15
        const size_t off = (size_t)(gk >> 3) * T64_SH + (((gk & 7) * 128) + d) * 8;
        *(uint4*)(dst + off) = *(const uint4*)&tl[d * 144 + gk * 8];
    }
}

// ---- main: 256-thread blocks (4 waves), 2 blocks/CU, BK=64 ----
__global__ __launch_bounds__(256, 2)
void attn_fwd11(const float* __restrict__ q,
                const unsigned short* __restrict__ kws,
                const unsigned short* __restrict__ vws,
                float* __restrict__ out)
{
    // K double-buffer (2x16KB) + V double-buffer (2x16KB) = 64 KB.
    __shared__ __align__(16) unsigned short smem[32768];
    unsigned short* const ks0 = smem;              // 8192 shorts
    unsigned short* const ks1 = smem + 8192;
    unsigned short* const vt0 = smem + 16384;
    unsigned short* const vt1 = smem + 24576;

    const int t    = threadIdx.x;          // 0..255
    const int w    = t >> 6;               // wave 0..3 = q-subtile
    const int lane = t & 63;
    const int ln   = lane & 31;
    const int half = lane >> 5;

    // pairing + XCD-exact mapping: blocks bid and bid+256 share a CU slot
    // and an XCD (bid%8); both map to the same h -> kvh = (bid%8 related).
    const int bid  = blockIdx.x;           // 0..511
    const int pair = bid & 255;
    const int late = bid >> 8;
    const int h    = (pair & 7) * 4 + ((pair >> 3) & 3);
    const int px   = pair >> 5;            // 0..7
    const int bx   = late ? (15 - px) : px;
    const int kvh  = h >> 2;

    const int q0    = bx * BQ;
    const int wq0   = q0 + w * 32;
    const int qrow  = wq0 + ln;
    const int wqmax = wq0 + 31;
    const int nit   = 2 * bx + 2;          // BK=64 iterations (2..32)

    // slice-major per-lane LDS read bases (shorts); reads are base + imm.
    const int kofs = half * 512 + ln * 8;    // K: [gl16][row64]
    const int vofs = half * 1024 + ln * 8;   // V: [gl8][d128]

    // linear staging sources: thread t covers bytes t*16 + j*4096 of tile.
    const unsigned short* const kgp = kws + (size_t)(kvh * 32) * T64_SH + t * 8;
    const unsigned short* const vgp = vws + (size_t)(kvh * 32) * T64_SH + t * 8;
    const int wofs = w * 512;              // wave-uniform LDS offset (shorts)

    // all-ones bf16 B fragment for the l row-sum MFMA
    short8 onesv;
    {
        union { short8 v; unsigned int u[4]; } uo;
        uo.u[0] = uo.u[1] = uo.u[2] = uo.u[3] = 0x3F803F80u;
        onesv = uo.v;
    }

#define ISSUE(tix, kb_, vb_) do { \
    const unsigned short* kg_ = kgp + (size_t)(tix) * T64_SH; \
    const unsigned short* vg_ = vgp + (size_t)(tix) * T64_SH; \
    gload_lds16(kg_,        (kb_) + wofs); \
    gload_lds16(kg_ + 2048, (kb_) + wofs + 2048); \
    gload_lds16(kg_ + 4096, (kb_) + wofs + 4096); \
    gload_lds16(kg_ + 6144, (kb_) + wofs + 6144); \
    gload_lds16(vg_,        (vb_) + wofs); \
    gload_lds16(vg_ + 2048, (vb_) + wofs + 2048); \
    gload_lds16(vg_ + 4096, (vb_) + wofs + 4096); \
    gload_lds16(vg_ + 6144, (vb_) + wofs + 6144); \
} while (0)

    // ---- Q fragments, pre-scaled by SCALE*log2(e) ----
    short8 qf[8];
    {
        const float* qr = q + ((size_t)qrow * NH + h) * HD;
        #pragma unroll
        for (int k0 = 0; k0 < 8; ++k0) {
            const float* p4 = qr + k0 * 16 + half * 8;
            const float4 a = *(const float4*)(p4);
            const float4 b = *(const float4*)(p4 + 4);
            union { short8 v; unsigned int u[4]; } uu;
            uu.u[0] = f2bf2(a.x * QS, a.y * QS);
            uu.u[1] = f2bf2(a.z * QS, a.w * QS);
            uu.u[2] = f2bf2(b.x * QS, b.y * QS);
            uu.u[3] = f2bf2(b.z * QS, b.w * QS);
            qf[k0] = uu.v;
        }
    }

    float16 o0, o1, o2, o3, lacc, z16;
    #pragma unroll
    for (int i = 0; i < 16; ++i) {
        o0[i] = 0.f; o1[i] = 0.f; o2[i] = 0.f; o3[i] = 0.f;
        lacc[i] = 0.f; z16[i] = 0.f;
    }

    ISSUE(0, ks0, vt0);
    ISSUE(1, ks1, vt1);                    // nit >= 2 always

    for (int it = 0; it < nit; ++it) {
        const int cur = it & 1;
        const unsigned short* ksc = (cur ? ks1 : ks0) + kofs;
        const unsigned short* vtc = (cur ? vt1 : vt0) + vofs;

        // tile it complete; tile it+1's 8 loads may stay in flight
        if (it + 1 < nit) asm volatile("s_waitcnt vmcnt(8)" ::: "memory");
        else              asm volatile("s_waitcnt vmcnt(0)" ::: "memory");
        __builtin_amdgcn_s_barrier();
        __builtin_amdgcn_sched_barrier(0);

        const int j0 = it * 64;
        if (j0 <= wqmax) {
            // ---- S^T = K Q^T (pre-scaled, log2 domain) ----
            float16 st0, st1;
            {
                const short8 a0 = *(const short8*)&ksc[0];
                const short8 a1 = *(const short8*)&ksc[256];
                st0 = __builtin_amdgcn_mfma_f32_32x32x16_bf16(a0, qf[0], z16, 0, 0, 0);
                st1 = __builtin_amdgcn_mfma_f32_32x32x16_bf16(a1, qf[0], z16, 0, 0, 0);
            }
            #pragma unroll
            for (int k0 = 1; k0 < 8; ++k0) {
                const short8 a0 = *(const short8*)&ksc[k0 * 1024];
                const short8 a1 = *(const short8*)&ksc[k0 * 1024 + 256];
                st0 = __builtin_amdgcn_mfma_f32_32x32x16_bf16(a0, qf[k0], st0, 0, 0, 0);
                st1 = __builtin_amdgcn_mfma_f32_32x32x16_bf16(a1, qf[k0], st1, 0, 0, 0);
            }

            // ---- causal mask (diagonal tiles only) ----
            if ((j0 + 63) > wq0) {
                #pragma unroll
                for (int r = 0; r < 16; ++r) {
                    const int kl = (r & 3) + 8 * (r >> 2) + 4 * half;
                    if (j0 + kl > qrow)      st0[r] = -1e30f;
                    if (j0 + 32 + kl > qrow) st1[r] = -1e30f;
                }
            }

#define PV_STEP(afx, kc) do { \
    const short8 bv0 = *(const short8*)&vtc[(kc) * 2048]; \
    const short8 bv1 = *(const short8*)&vtc[(kc) * 2048 + 256]; \
    const short8 bv2 = *(const short8*)&vtc[(kc) * 2048 + 512]; \
    const short8 bv3 = *(const short8*)&vtc[(kc) * 2048 + 768]; \
    o0 = __builtin_amdgcn_mfma_f32_32x32x16_bf16(afx, bv0, o0, 0, 0, 0); \
    o1 = __builtin_amdgcn_mfma_f32_32x32x16_bf16(afx, bv1, o1, 0, 0, 0); \
    o2 = __builtin_amdgcn_mfma_f32_32x32x16_bf16(afx, bv2, o2, 0, 0, 0); \
    o3 = __builtin_amdgcn_mfma_f32_32x32x16_bf16(afx, bv3, o3, 0, 0, 0); \
    lacc = __builtin_amdgcn_mfma_f32_32x32x16_bf16(afx, onesv, lacc, 0, 0, 0); \
} while (0)

            // ---- half 0: P = exp2(st0) (unnormalized), PV over kc 0,1 ----
            #pragma unroll
            for (int r = 0; r < 16; ++r) st0[r] = exp2f(st0[r]);
            short8 af0, af1;
            MAKE_AF(af0, st0, 0);
            MAKE_AF(af1, st0, 8);
            PV_STEP(af0, 0);
            PV_STEP(af1, 1);

            // ---- half 1: exp2(st1) overlaps half-0 PV; PV over kc 2,3 ----
            #pragma unroll
            for (int r = 0; r < 16; ++r) st1[r] = exp2f(st1[r]);
            short8 af2, af3;
            MAKE_AF(af2, st1, 0);
            MAKE_AF(af3, st1, 8);
            PV_STEP(af2, 2);
            PV_STEP(af3, 3);
#undef PV_STEP
        }

        // all LDS reads of buf[cur] complete before it is restaged
        asm volatile("s_waitcnt lgkmcnt(0)" ::: "memory");
        __builtin_amdgcn_s_barrier();
        __builtin_amdgcn_sched_barrier(0);
        if (it + 2 < nit) ISSUE(it + 2, cur ? ks1 : ks0, cur ? vt1 : vt0);
    }

    // ---- epilogue: each wave owns all keys for its rows -> direct store ----
    #pragma unroll
    for (int r = 0; r < 16; ++r) {
        const int rl = (r & 3) + 8 * (r >> 2) + 4 * half;
        const float inv = 1.f / lacc[r];
        float* orow = out + ((size_t)(wq0 + rl) * NH + h) * HD;
        orow[ln]      = o0[r] * inv;
        orow[32 + ln] = o1[r] * inv;
        orow[64 + ln] = o2[r] * inv;
        orow[96 + ln] = o3[r] * inv;
    }
#undef ISSUE
}

// ---- fallback (round-4 kernel, no workspace needed) ----
__global__ __launch_bounds__(256, 2)
void attn_fwd_fb(const float* __restrict__ q,
                 const float* __restrict__ k,
                 const float* __restrict__ v,
                 float* __restrict__ out)
{
    __shared__ unsigned short ks[64 * KSS];
    __shared__ unsigned short vt[HD * VTSF];
    __shared__ unsigned short ps[4][32 * PSS];
    __shared__ float          alf[4][32];

    const int t    = threadIdx.x;
    const int w    = t >> 6;
    const int lane = t & 63;
    const int ln   = lane & 31;
    const int half = lane >> 5;
    const int h    = blockIdx.y;
    const int kvh  = h >> 2;
    const int q0   = blockIdx.x * BQ;
    const int wq0  = q0 + w * 32;
    const int qrow = wq0 + ln;

    short8 qf[8];
    {
        const float* qr = q + ((size_t)qrow * NH + h) * HD;
        #pragma unroll
        for (int k0 = 0; k0 < 8; ++k0) {
            const float* p4 = qr + k0 * 16 + half * 8;
            const float4 a = *(const float4*)(p4);
            const float4 b = *(const float4*)(p4 + 4);
            union { short8 v; unsigned int u[4]; } uu;
            uu.u[0] = f2bf2(a.x, a.y);
            uu.u[1] = f2bf2(a.z, a.w);
            uu.u[2] = f2bf2(b.x, b.y);
            uu.u[3] = f2bf2(b.z, b.w);
            qf[k0] = uu.v;
        }
    }

    float16 o0, o1, o2, o3;
    #pragma unroll
    for (int i = 0; i < 16; ++i) { o0[i] = 0.f; o1[i] = 0.f; o2[i] = 0.f; o3[i] = 0.f; }
    float m_run = -1e30f, l_run = 0.f;
    const int ntiles = (q0 + BQ) / 64;
    const int wqmax  = wq0 + 31;

    for (int it = 0; it < ntiles; ++it) {
        const int j0 = it * 64;
        __syncthreads();
        {
            const int key = t >> 2;
            const int db  = (t & 3) * 4;
            const float* kr = k + ((size_t)(j0 + key) * NKVH + kvh) * HD;
            #pragma unroll
            for (int r2 = 0; r2 < 8; ++r2) {
                const int d = db + r2 * 16;
                const float4 a = *(const float4*)(kr + d);
                *(unsigned int*)&ks[key * KSS + d]     = f2bf2(a.x, a.y);
                *(unsigned int*)&ks[key * KSS + d + 2] = f2bf2(a.z, a.w);
            }
        }
        {
            const int kp = (t & 31) * 2;
            const int db = (t >> 5) * 4;
            const float* vr0 = v + ((size_t)(j0 + kp) * NKVH + kvh) * HD;
            const float* vr1 = vr0 + NKVH * HD;
            #pragma unroll
            for (int r2 = 0; r2 < 4; ++r2) {
                const int d = db + r2 * 32;
                const float4 a = *(const float4*)(vr0 + d);
                const float4 b = *(const float4*)(vr1 + d);
                *(unsigned int*)&vt[(d + 0) * VTSF + kp] = f2bf2(a.x, b.x);
                *(unsigned int*)&vt[(d + 1) * VTSF + kp] = f2bf2(a.y, b.y);
                *(unsigned int*)&vt[(d + 2) * VTSF + kp] = f2bf2(a.z, b.z);
                *(unsigned int*)&vt[(d + 3) * VTSF + kp] = f2bf2(a.w, b.w);
            }
        }
        __syncthreads();
        if (j0 > wqmax) continue;

        float16 st0, st1;
        #pragma unroll
        for (int i = 0; i < 16; ++i) { st0[i] = 0.f; st1[i] = 0.f; }
        #pragma unroll
        for (int k0 = 0; k0 < 8; ++k0) {
            const short8 a0 = *(const short8*)&ks[ln * KSS + k0 * 16 + half * 8];
            const short8 a1 = *(const short8*)&ks[(32 + ln) * KSS + k0 * 16 + half * 8];
            st0 = __builtin_amdgcn_mfma_f32_32x32x16_bf16(a0, qf[k0], st0, 0, 0, 0);
            st1 = __builtin_amdgcn_mfma_f32_32x32x16_bf16(a1, qf[k0], st1, 0, 0, 0);
        }
        const bool need_mask = (j0 + 63) > wq0;
        float mt = -1e30f;
        #pragma unroll
        for (int r = 0; r < 16; ++r) {
            const int kl = (r & 3) + 8 * (r >> 2) + 4 * half;
            float a0 = st0[r] * SCALE;
            float a1 = st1[r] * SCALE;
            if (need_mask) {
                if (j0 + kl > qrow)      a0 = -1e30f;
                if (j0 + 32 + kl > qrow) a1 = -1e30f;
            }
            st0[r] = a0; st1[r] = a1;
            mt = fmaxf(mt, fmaxf(a0, a1));
        }
        mt = fmaxf(mt, __shfl_xor(mt, 32, 64));
        const float mn = fmaxf(m_run, mt);
        float sm = 0.f;
        #pragma unroll
        for (int r = 0; r < 16; ++r) {
            const float e0 = __expf(st0[r] - mn);
            const float e1 = __expf(st1[r] - mn);
            st0[r] = e0; st1[r] = e1;
            sm += e0 + e1;
        }
        sm += __shfl_xor(sm, 32, 64);
        const float alpha = __expf(m_run - mn);
        m_run = mn;
        l_run = l_run * alpha + sm;

        unsigned short* psw = ps[w];
        #pragma unroll
        for (int r = 0; r < 16; r += 2) {
            const int kl = (r & 3) + 8 * (r >> 2) + 4 * half;
            *(unsigned int*)&psw[ln * PSS + kl]      = f2bf2(st0[r], st0[r + 1]);
            *(unsigned int*)&psw[ln * PSS + 32 + kl] = f2bf2(st1[r], st1[r + 1]);
        }
        if (half == 0) alf[w][ln] = alpha;
        #pragma unroll
        for (int r = 0; r < 16; ++r) {
            const int rl = (r & 3) + 8 * (r >> 2) + 4 * half;
            const float ar = alf[w][rl];
            o0[r] *= ar; o1[r] *= ar; o2[r] *= ar; o3[r] *= ar;
        }
        short8 af[4];
        #pragma unroll
        for (int kc = 0; kc < 4; ++kc)
            af[kc] = *(const short8*)&psw[ln * PSS + kc * 16 + half * 8];
        #pragma unroll
        for (int kc = 0; kc < 4; ++kc) {
            const short8 bv0 = *(const short8*)&vt[(ln)      * VTSF + kc * 16 + half * 8];
            const short8 bv1 = *(const short8*)&vt[(32 + ln) * VTSF + kc * 16 + half * 8];
            const short8 bv2 = *(const short8*)&vt[(64 + ln) * VTSF + kc * 16 + half * 8];
            const short8 bv3 = *(const short8*)&vt[(96 + ln) * VTSF + kc * 16 + half * 8];
            o0 = __builtin_amdgcn_mfma_f32_32x32x16_bf16(af[kc], bv0, o0, 0, 0, 0);
            o1 = __builtin_amdgcn_mfma_f32_32x32x16_bf16(af[kc], bv1, o1, 0, 0, 0);
            o2 = __builtin_amdgcn_mfma_f32_32x32x16_bf16(af[kc], bv2, o2, 0, 0, 0);
            o3 = __builtin_amdgcn_mfma_f32_32x32x16_bf16(af[kc], bv3, o3, 0, 0, 0);
        }
    }

    if (half == 0) alf[w][ln] = l_run;
    __builtin_amdgcn_s_waitcnt(0);
    #pragma unroll
    for (int r = 0; r < 16; ++r) {
        const int rl = (r & 3) + 8 * (r >> 2) + 4 * half;
        const float inv = 1.f / alf[w][rl];
        float* orow = out + ((size_t)(wq0 + rl) * NH + h) * HD;
        orow[ln]      = o0[r] * inv;
        orow[32 + ln] = o1[r] * inv;
        orow[64 + ln] = o2[r] * inv;
        orow[96 + ln] = o3[r] * inv;
    }
}

extern "C" void kernel_launch(void* const* d_in, const int* in_sizes, int n_in,
                              void* d_out, int out_size, void* d_ws, size_t ws_size,
                              hipStream_t stream) {
    const float* q = (const float*)d_in[0];
    const float* k = (const float*)d_in[1];
    const float* v = (const float*)d_in[2];
    float* out = (float*)d_out;
    if (ws_size >= (size_t)WS_NEED) {
        unsigned short* kws = (unsigned short*)d_ws;
        unsigned short* vws = kws + KB_ELEMS;
        cvt_kv4<<<256, 256, 0, stream>>>(k, v, kws, vws);
        attn_fwd11<<<512, 256, 0, stream>>>(q, kws, vws, out);
    } else {
        attn_fwd_fb<<<dim3(SEQ / BQ, NH), 256, 0, stream>>>(q, k, v, out);
    }
}

// Round 11
// 149.939 us; speedup vs baseline: 1.0105x; 1.0105x over previous
//
#include <hip/hip_runtime.h>

// Causal GQA attention prefill, fp32 in/out, MFMA 32x32x16 bf16 compute.
// S=2048, H=32, KVH=8 (rep=4), D=128.
// Round 16. Model from rounds 12-15: per-CU throughput is CONSTANT at
// ~1.9 wave-units/us (unit = 32q x 64keys) across wave counts (1-2/SIMD),
// conflict elimination, addr-VALU elimination, ILP and TLP restructures.
// => binder is the shared per-CU LDS path (each wave pulls 32 KB/unit
// through it; MFMA/VALU pipes are 21%/26% busy). This round HALVES LDS
// traffic:
//   1) V comes straight from the L2-resident, XCD-local slice-major
//      workspace into REGISTERS (16 coalesced global_load_dwordx4 per wave
//      per unit, batched: kc0 before QK, kc1-3 after QK -> L2 latency
//      hidden under QK+softmax). V LDS buffers and their staging deleted.
//   2) K-fragments batch-hoisted into ka[16] (16-deep outstanding ds_reads).
//   3) LDS = K double-buffer only (2x32KB); epilogue obuf aliases it.
// Kept from round 12 (best, 69.3 us): 512-thread persistent 2-phase blocks
// (q-tiles px then 15-px, 17 BK=128 iters), 2-group key split, slice-major
// workspaces, unnormalized softmax (exp2 direct, QS folded into Q),
// ones-MFMA row-sum, counted-vmcnt K staging, XCD-exact h map.

#define SEQ   2048
#define NH    32
#define NKVH  8
#define HD    128
#define BQ    128
#define BK    128    // staged keys per iteration (2 wave-groups x 64)
#define KSS   136    // fallback kernel K stride
#define VTSF  72     // fallback kernel V stride
#define PSS   72     // fallback ps stride
#define SCALE 0.08838834764831845f
#define QS    (0.08838834764831845f * 1.4426950408889634f)   // SCALE * log2(e)

#define TILE_SH 16384                        // shorts per 128x128 bf16 tile
#define KB_ELEMS (SEQ * NKVH * HD)           // 2,097,152 ushorts
#define WS_NEED  (2u * KB_ELEMS * 2u)        // kws + vws, bytes

typedef __attribute__((ext_vector_type(8)))  short short8;
typedef __attribute__((ext_vector_type(16))) float float16;
typedef __attribute__((ext_vector_type(2)))  unsigned int uint2v;

__device__ __forceinline__ unsigned short f2bf(float f) {
    union { float f; unsigned int i; } x; x.f = f;
    unsigned int r = x.i + 0x7fffu + ((x.i >> 16) & 1u);   // RNE
    return (unsigned short)(r >> 16);
}
__device__ __forceinline__ unsigned int f2bf2(float lo, float hi) {
    return (unsigned int)f2bf(lo) | ((unsigned int)f2bf(hi) << 16);
}
__device__ __forceinline__ unsigned int cvt_pk_bf16(float lo, float hi) {
    unsigned int r;
    asm("v_cvt_pk_bf16_f32 %0, %1, %2" : "=v"(r) : "v"(lo), "v"(hi));
    return r;
}

// direct global->LDS copy, 16 B per lane; LDS dest is wave-uniform base,
// HW adds lane*16; global src is per-lane.
__device__ __forceinline__ void gload_lds16(const unsigned short* g, unsigned short* l) {
    __builtin_amdgcn_global_load_lds(
        (const __attribute__((address_space(1))) void*)g,
        (__attribute__((address_space(3))) void*)l, 16, 0, 0);
}

#if __has_builtin(__builtin_amdgcn_permlane32_swap)
#define PLSWAP(a, b, xout, yout) do { \
    uint2v r_ = __builtin_amdgcn_permlane32_swap((a), (b), false, false); \
    (xout) = r_.x; (yout) = r_.y; } while (0)
#else
#define PLSWAP(a, b, xout, yout) do { \
    unsigned int a_ = (a), b_ = (b); \
    asm volatile("s_nop 1\n\tv_permlane32_swap_b32 %0, %1" : "+v"(a_), "+v"(b_)); \
    (xout) = a_; (yout) = b_; } while (0)
#endif

#define MAKE_AF(dst, sv, b) do { \
    const unsigned int p0_ = cvt_pk_bf16(sv[(b) + 0], sv[(b) + 1]); \
    const unsigned int p1_ = cvt_pk_bf16(sv[(b) + 2], sv[(b) + 3]); \
    const unsigned int p2_ = cvt_pk_bf16(sv[(b) + 4], sv[(b) + 5]); \
    const unsigned int p3_ = cvt_pk_bf16(sv[(b) + 6], sv[(b) + 7]); \
    unsigned int w0_, w1_, w2_, w3_; \
    PLSWAP(p0_, p2_, w0_, w2_); \
    PLSWAP(p1_, p3_, w1_, w3_); \
    union { short8 v; unsigned int u[4]; } uu_; \
    uu_.u[0] = w0_; uu_.u[1] = w1_; uu_.u[2] = w2_; uu_.u[3] = w3_; \
    (dst) = uu_.v; } while (0)

// ---- prep: build slice-major bf16 workspaces ----
// kws[kvh][tile16][gl16][row128] : 8-short unit (gl*128+row)*8 holds
//   K[tile*128+row][d = gl*8 .. gl*8+8) as bf16.
// vws[kvh][tile16][gl16][d128]   : unit (gl*128+d)*8 holds
//   V[key = tile*128+gl*8+e][d], e=0..7 (V^T key-slice at dim d).
__global__ __launch_bounds__(256)
void cvt_kv3(const float* __restrict__ k, const float* __restrict__ v,
             unsigned short* __restrict__ kws, unsigned short* __restrict__ vws)
{
    __shared__ unsigned short tl[128 * 144];
    const int t = threadIdx.x;
    if (blockIdx.x < 128) {                  // ---- K slice-major ----
        const int bid = blockIdx.x;
        const int kvh = bid >> 4, tile = bid & 15;
        unsigned short* dst = kws + (size_t)bid * TILE_SH;
        #pragma unroll
        for (int r = 0; r < 8; ++r) {
            const int gid = r * 256 + t;     // 0..2047
            const int gl = gid >> 7, row = gid & 127;
            const float* src =
                k + ((size_t)(tile * 128 + row) * NKVH + kvh) * HD + gl * 8;
            const float4 a = *(const float4*)(src);
            const float4 b = *(const float4*)(src + 4);
            uint4 o;
            o.x = f2bf2(a.x, a.y); o.y = f2bf2(a.z, a.w);
            o.z = f2bf2(b.x, b.y); o.w = f2bf2(b.z, b.w);
            *(uint4*)(dst + (size_t)gid * 8) = o;
        }
        return;
    }
    // ---- V transpose + slice-major ----
    const int bid = blockIdx.x - 128;
    const int kvh = bid >> 4, tile = bid & 15;
    const int dp  = (t & 63) * 2;
    const int k0q = t >> 6;
    #pragma unroll
    for (int r = 0; r < 32; ++r) {
        const int key = k0q + r * 4;         // 0..127
        const float2 a =
            *(const float2*)(v + ((size_t)(tile * 128 + key) * NKVH + kvh) * HD + dp);
        tl[dp * 144 + key]       = f2bf(a.x);
        tl[(dp + 1) * 144 + key] = f2bf(a.y);
    }
    __syncthreads();
    unsigned short* dst = vws + (size_t)bid * TILE_SH;
    #pragma unroll
    for (int r = 0; r < 8; ++r) {
        const int gid = r * 256 + t;
        const int gl = gid >> 7, d = gid & 127;
        *(uint4*)(dst + (size_t)gid * 8) = *(const uint4*)&tl[d * 144 + gl * 8];
    }
}

// ---- main: persistent 512-thread blocks, 2 q-tiles each, 17 iters total ----
__global__ __launch_bounds__(512, 1)
void attn_fwd12(const float* __restrict__ q,
                const unsigned short* __restrict__ kws,
                const unsigned short* __restrict__ vws,
                float* __restrict__ out)
{
    // K double-buffer only (2x32KB = 64 KB); epilogue obuf (64 KB) aliases.
    __shared__ __align__(16) unsigned char smem[65536];
    __shared__ float Sl[2][4][32];
    unsigned short* const ks0 = (unsigned short*)smem;
    unsigned short* const ks1 = (unsigned short*)(smem + 32768);
    float*          const obuf = (float*)smem;

    const int t    = threadIdx.x;          // 0..511
    const int w    = t >> 6;               // wave 0..7
    const int lane = t & 63;
    const int ln   = lane & 31;
    const int half = lane >> 5;
    const int g    = w >> 2;               // key-group 0/1
    const int w3   = w & 3;                // q-subtile 0..3

    // XCD-exact mapping: blocks with bid%8==x share kvh==x on XCD x.
    const int bid = blockIdx.x;            // 0..255
    const int h   = (bid & 7) * 4 + ((bid >> 3) & 3);
    const int px  = bid >> 5;              // 0..7
    const int kvh = h >> 2;

    // slice-major per-lane bases (shorts)
    const int kofs = half * 1024 + (g * 64 + ln) * 8;   // K LDS: [gl][row]
    const int vofs = (g * 8 + half) * 1024 + ln * 8;    // V global: [gl][d]

    // staging source: thread t covers bytes t*16 + j*8192 of the K tile.
    const unsigned short* const kgp = kws + (size_t)(kvh * 16) * TILE_SH + t * 8;
    const unsigned short* const vt0 = vws + (size_t)(kvh * 16) * TILE_SH + vofs;
    const int wofs = w * 512;              // wave-uniform LDS offset (shorts)

    // all-ones bf16 B fragment for the l row-sum MFMA
    short8 onesv;
    {
        union { short8 v; unsigned int u[4]; } uo;
        uo.u[0] = uo.u[1] = uo.u[2] = uo.u[3] = 0x3F803F80u;
        onesv = uo.v;
    }

#define ISSUE(tix, kb_) do { \
    const unsigned short* kg_ = kgp + (size_t)(tix) * TILE_SH; \
    gload_lds16(kg_,         (kb_) + wofs); \
    gload_lds16(kg_ +  4096, (kb_) + wofs + 4096); \
    gload_lds16(kg_ +  8192, (kb_) + wofs + 8192); \
    gload_lds16(kg_ + 12288, (kb_) + wofs + 12288); \
} while (0)

#define PV_R(afx, b0, b1, b2, b3) do { \
    o0 = __builtin_amdgcn_mfma_f32_32x32x16_bf16(afx, b0, o0, 0, 0, 0); \
    o1 = __builtin_amdgcn_mfma_f32_32x32x16_bf16(afx, b1, o1, 0, 0, 0); \
    o2 = __builtin_amdgcn_mfma_f32_32x32x16_bf16(afx, b2, o2, 0, 0, 0); \
    o3 = __builtin_amdgcn_mfma_f32_32x32x16_bf16(afx, b3, o3, 0, 0, 0); \
    lacc = __builtin_amdgcn_mfma_f32_32x32x16_bf16(afx, onesv, lacc, 0, 0, 0); \
} while (0)

    for (int ph = 0; ph < 2; ++ph) {
        const int bx    = ph ? (15 - px) : px;
        const int q0    = bx * BQ;
        const int wq0   = q0 + w3 * 32;
        const int qrow  = wq0 + ln;
        const int wqmax = wq0 + 31;
        const int nit   = bx + 1;          // BK=128 iterations

        // ---- Q fragments, pre-scaled by SCALE*log2(e) ----
        short8 qf[8];
        {
            const float* qr = q + ((size_t)qrow * NH + h) * HD;
            #pragma unroll
            for (int k0 = 0; k0 < 8; ++k0) {
                const float* p4 = qr + k0 * 16 + half * 8;
                const float4 a = *(const float4*)(p4);
                const float4 b = *(const float4*)(p4 + 4);
                union { short8 v; unsigned int u[4]; } uu;
                uu.u[0] = f2bf2(a.x * QS, a.y * QS);
                uu.u[1] = f2bf2(a.z * QS, a.w * QS);
                uu.u[2] = f2bf2(b.x * QS, b.y * QS);
                uu.u[3] = f2bf2(b.z * QS, b.w * QS);
                qf[k0] = uu.v;
            }
        }

        float16 o0, o1, o2, o3, lacc, z16;
        #pragma unroll
        for (int i = 0; i < 16; ++i) {
            o0[i] = 0.f; o1[i] = 0.f; o2[i] = 0.f; o3[i] = 0.f;
            lacc[i] = 0.f; z16[i] = 0.f;
        }

        ISSUE(0, ks0);
        if (nit > 1) ISSUE(1, ks1);

        for (int it = 0; it < nit; ++it) {
            const int cur = it & 1;
            const unsigned short* ksc = (cur ? ks1 : ks0) + kofs;
            const unsigned short* vg  = vt0 + (size_t)it * TILE_SH;

            // K(it) staged; K(it+1)'s 4 loads may stay in flight.
            if (it + 1 < nit) asm volatile("s_waitcnt vmcnt(4)" ::: "memory");
            else              asm volatile("s_waitcnt vmcnt(0)" ::: "memory");
            __builtin_amdgcn_s_barrier();
            __builtin_amdgcn_sched_barrier(0);

            const int j0g = it * BK + g * 64;   // this wave-group's key base
            if (j0g <= wqmax) {
                // ---- V kc0 batch: global->regs, issued before QK ----
                const short8 vv00 = *(const short8*)&vg[0];
                const short8 vv01 = *(const short8*)&vg[256];
                const short8 vv02 = *(const short8*)&vg[512];
                const short8 vv03 = *(const short8*)&vg[768];

                // ---- K batch-hoist + S^T = K Q^T (log2 domain) ----
                short8 ka[16];
                #pragma unroll
                for (int k0 = 0; k0 < 8; ++k0) {
                    ka[2 * k0]     = *(const short8*)&ksc[k0 * 2048];
                    ka[2 * k0 + 1] = *(const short8*)&ksc[k0 * 2048 + 256];
                }
                float16 st0, st1;
                st0 = __builtin_amdgcn_mfma_f32_32x32x16_bf16(ka[0], qf[0], z16, 0, 0, 0);
                st1 = __builtin_amdgcn_mfma_f32_32x32x16_bf16(ka[1], qf[0], z16, 0, 0, 0);
                #pragma unroll
                for (int k0 = 1; k0 < 8; ++k0) {
                    st0 = __builtin_amdgcn_mfma_f32_32x32x16_bf16(ka[2 * k0],     qf[k0], st0, 0, 0, 0);
                    st1 = __builtin_amdgcn_mfma_f32_32x32x16_bf16(ka[2 * k0 + 1], qf[k0], st1, 0, 0, 0);
                }

                // ---- V kc1..kc3 batches (ka dead, regs free); used >=300cyc later
                const short8 vv10 = *(const short8*)&vg[2048];
                const short8 vv11 = *(const short8*)&vg[2048 + 256];
                const short8 vv12 = *(const short8*)&vg[2048 + 512];
                const short8 vv13 = *(const short8*)&vg[2048 + 768];
                const short8 vv20 = *(const short8*)&vg[4096];
                const short8 vv21 = *(const short8*)&vg[4096 + 256];
                const short8 vv22 = *(const short8*)&vg[4096 + 512];
                const short8 vv23 = *(const short8*)&vg[4096 + 768];
                const short8 vv30 = *(const short8*)&vg[6144];
                const short8 vv31 = *(const short8*)&vg[6144 + 256];
                const short8 vv32 = *(const short8*)&vg[6144 + 512];
                const short8 vv33 = *(const short8*)&vg[6144 + 768];

                // ---- causal mask (diagonal tiles only) ----
                if ((j0g + 63) > wq0) {
                    #pragma unroll
                    for (int r = 0; r < 16; ++r) {
                        const int kl = (r & 3) + 8 * (r >> 2) + 4 * half;
                        if (j0g + kl > qrow)      st0[r] = -1e30f;
                        if (j0g + 32 + kl > qrow) st1[r] = -1e30f;
                    }
                }

                // ---- half 0: P = exp2(st0), PV over kc 0,1 ----
                #pragma unroll
                for (int r = 0; r < 16; ++r) st0[r] = exp2f(st0[r]);
                short8 af0, af1;
                MAKE_AF(af0, st0, 0);
                MAKE_AF(af1, st0, 8);
                PV_R(af0, vv00, vv01, vv02, vv03);
                PV_R(af1, vv10, vv11, vv12, vv13);

                // ---- half 1: exp2(st1) overlaps half-0 PV; PV over kc 2,3 ----
                #pragma unroll
                for (int r = 0; r < 16; ++r) st1[r] = exp2f(st1[r]);
                short8 af2, af3;
                MAKE_AF(af2, st1, 0);
                MAKE_AF(af3, st1, 8);
                PV_R(af2, vv20, vv21, vv22, vv23);
                PV_R(af3, vv30, vv31, vv32, vv33);
            }

            // all LDS reads of ks[cur] complete before it is restaged
            asm volatile("s_waitcnt lgkmcnt(0)" ::: "memory");
            __builtin_amdgcn_s_barrier();
            __builtin_amdgcn_sched_barrier(0);
            if (it + 2 < nit) ISSUE(it + 2, cur ? ks1 : ks0);
        }

        // ---- epilogue: l is in lacc (identical across ln); merge groups ----
        if (ln == 0) {
            #pragma unroll
            for (int r = 0; r < 16; ++r)
                Sl[g][w3][(r & 3) + 8 * (r >> 2) + 4 * half] = lacc[r];
        }
        __syncthreads();

        if (g == 1) {
            #pragma unroll
            for (int r = 0; r < 16; ++r) {
                const int rl = (r & 3) + 8 * (r >> 2) + 4 * half;
                float* ob = &obuf[(size_t)(w3 * 32 + rl) * 128];
                ob[ln]      = o0[r];
                ob[32 + ln] = o1[r];
                ob[64 + ln] = o2[r];
                ob[96 + ln] = o3[r];
            }
        }
        __syncthreads();
        if (g == 0) {
            #pragma unroll
            for (int r = 0; r < 16; ++r) {
                const int rl = (r & 3) + 8 * (r >> 2) + 4 * half;
                const float inv = 1.f / (Sl[0][w3][rl] + Sl[1][w3][rl]);
                const float* ob = &obuf[(size_t)(w3 * 32 + rl) * 128];
                float* orow = out + ((size_t)(wq0 + rl) * NH + h) * HD;
                orow[ln]      = (o0[r] + ob[ln])      * inv;
                orow[32 + ln] = (o1[r] + ob[32 + ln]) * inv;
                orow[64 + ln] = (o2[r] + ob[64 + ln]) * inv;
                orow[96 + ln] = (o3[r] + ob[96 + ln]) * inv;
            }
        }
        __syncthreads();   // obuf reads done before next phase restages pool
    }
#undef PV_R
#undef ISSUE
}

// ---- fallback (round-4 kernel, no workspace needed) ----
__global__ __launch_bounds__(256, 2)
void attn_fwd_fb(const float* __restrict__ q,
                 const float* __restrict__ k,
                 const float* __restrict__ v,
                 float* __restrict__ out)
{
    __shared__ unsigned short ks[64 * KSS];
    __shared__ unsigned short vt[HD * VTSF];
    __shared__ unsigned short ps[4][32 * PSS];
    __shared__ float          alf[4][32];

    const int t    = threadIdx.x;
    const int w    = t >> 6;
    const int lane = t & 63;
    const int ln   = lane & 31;
    const int half = lane >> 5;
    const int h    = blockIdx.y;
    const int kvh  = h >> 2;
    const int q0   = blockIdx.x * BQ;
    const int wq0  = q0 + w * 32;
    const int qrow = wq0 + ln;

    short8 qf[8];
    {
        const float* qr = q + ((size_t)qrow * NH + h) * HD;
        #pragma unroll
        for (int k0 = 0; k0 < 8; ++k0) {
            const float* p4 = qr + k0 * 16 + half * 8;
            const float4 a = *(const float4*)(p4);
            const float4 b = *(const float4*)(p4 + 4);
            union { short8 v; unsigned int u[4]; } uu;
            uu.u[0] = f2bf2(a.x, a.y);
            uu.u[1] = f2bf2(a.z, a.w);
            uu.u[2] = f2bf2(b.x, b.y);
            uu.u[3] = f2bf2(b.z, b.w);
            qf[k0] = uu.v;
        }
    }

    float16 o0, o1, o2, o3;
    #pragma unroll
    for (int i = 0; i < 16; ++i) { o0[i] = 0.f; o1[i] = 0.f; o2[i] = 0.f; o3[i] = 0.f; }
    float m_run = -1e30f, l_run = 0.f;
    const int ntiles = (q0 + BQ) / 64;
    const int wqmax  = wq0 + 31;

    for (int it = 0; it < ntiles; ++it) {
        const int j0 = it * 64;
        __syncthreads();
        {
            const int key = t >> 2;
            const int db  = (t & 3) * 4;
            const float* kr = k + ((size_t)(j0 + key) * NKVH + kvh) * HD;
            #pragma unroll
            for (int r2 = 0; r2 < 8; ++r2) {
                const int d = db + r2 * 16;
                const float4 a = *(const float4*)(kr + d);
                *(unsigned int*)&ks[key * KSS + d]     = f2bf2(a.x, a.y);
                *(unsigned int*)&ks[key * KSS + d + 2] = f2bf2(a.z, a.w);
            }
        }
        {
            const int kp = (t & 31) * 2;
            const int db = (t >> 5) * 4;
            const float* vr0 = v + ((size_t)(j0 + kp) * NKVH + kvh) * HD;
            const float* vr1 = vr0 + NKVH * HD;
            #pragma unroll
            for (int r2 = 0; r2 < 4; ++r2) {
                const int d = db + r2 * 32;
                const float4 a = *(const float4*)(vr0 + d);
                const float4 b = *(const float4*)(vr1 + d);
                *(unsigned int*)&vt[(d + 0) * VTSF + kp] = f2bf2(a.x, b.x);
                *(unsigned int*)&vt[(d + 1) * VTSF + kp] = f2bf2(a.y, b.y);
                *(unsigned int*)&vt[(d + 2) * VTSF + kp] = f2bf2(a.z, b.z);
                *(unsigned int*)&vt[(d + 3) * VTSF + kp] = f2bf2(a.w, b.w);
            }
        }
        __syncthreads();
        if (j0 > wqmax) continue;

        float16 st0, st1;
        #pragma unroll
        for (int i = 0; i < 16; ++i) { st0[i] = 0.f; st1[i] = 0.f; }
        #pragma unroll
        for (int k0 = 0; k0 < 8; ++k0) {
            const short8 a0 = *(const short8*)&ks[ln * KSS + k0 * 16 + half * 8];
            const short8 a1 = *(const short8*)&ks[(32 + ln) * KSS + k0 * 16 + half * 8];
            st0 = __builtin_amdgcn_mfma_f32_32x32x16_bf16(a0, qf[k0], st0, 0, 0, 0);
            st1 = __builtin_amdgcn_mfma_f32_32x32x16_bf16(a1, qf[k0], st1, 0, 0, 0);
        }
        const bool need_mask = (j0 + 63) > wq0;
        float mt = -1e30f;
        #pragma unroll
        for (int r = 0; r < 16; ++r) {
            const int kl = (r & 3) + 8 * (r >> 2) + 4 * half;
            float a0 = st0[r] * SCALE;
            float a1 = st1[r] * SCALE;
            if (need_mask) {
                if (j0 + kl > qrow)      a0 = -1e30f;
                if (j0 + 32 + kl > qrow) a1 = -1e30f;
            }
            st0[r] = a0; st1[r] = a1;
            mt = fmaxf(mt, fmaxf(a0, a1));
        }
        mt = fmaxf(mt, __shfl_xor(mt, 32, 64));
        const float mn = fmaxf(m_run, mt);
        float sm = 0.f;
        #pragma unroll
        for (int r = 0; r < 16; ++r) {
            const float e0 = __expf(st0[r] - mn);
            const float e1 = __expf(st1[r] - mn);
            st0[r] = e0; st1[r] = e1;
            sm += e0 + e1;
        }
        sm += __shfl_xor(sm, 32, 64);
        const float alpha = __expf(m_run - mn);
        m_run = mn;
        l_run = l_run * alpha + sm;

        unsigned short* psw = ps[w];
        #pragma unroll
        for (int r = 0; r < 16; r += 2) {
            const int kl = (r & 3) + 8 * (r >> 2) + 4 * half;
            *(unsigned int*)&psw[ln * PSS + kl]      = f2bf2(st0[r], st0[r + 1]);
            *(unsigned int*)&psw[ln * PSS + 32 + kl] = f2bf2(st1[r], st1[r + 1]);
        }
        if (half == 0) alf[w][ln] = alpha;
        #pragma unroll
        for (int r = 0; r < 16; ++r) {
            const int rl = (r & 3) + 8 * (r >> 2) + 4 * half;
            const float ar = alf[w][rl];
            o0[r] *= ar; o1[r] *= ar; o2[r] *= ar; o3[r] *= ar;
        }
        short8 af[4];
        #pragma unroll
        for (int kc = 0; kc < 4; ++kc)
            af[kc] = *(const short8*)&psw[ln * PSS + kc * 16 + half * 8];
        #pragma unroll
        for (int kc = 0; kc < 4; ++kc) {
            const short8 bv0 = *(const short8*)&vt[(ln)      * VTSF + kc * 16 + half * 8];
            const short8 bv1 = *(const short8*)&vt[(32 + ln) * VTSF + kc * 16 + half * 8];
            const short8 bv2 = *(const short8*)&vt[(64 + ln) * VTSF + kc * 16 + half * 8];
            const short8 bv3 = *(const short8*)&vt[(96 + ln) * VTSF + kc * 16 + half * 8];
            o0 = __builtin_amdgcn_mfma_f32_32x32x16_bf16(af[kc], bv0, o0, 0, 0, 0);
            o1 = __builtin_amdgcn_mfma_f32_32x32x16_bf16(af[kc], bv1, o1, 0, 0, 0);
            o2 = __builtin_amdgcn_mfma_f32_32x32x16_bf16(af[kc], bv2, o2, 0, 0, 0);
            o3 = __builtin_amdgcn_mfma_f32_32x32x16_bf16(af[kc], bv3, o3, 0, 0, 0);
        }
    }

    if (half == 0) alf[w][ln] = l_run;
    __builtin_amdgcn_s_waitcnt(0);
    #pragma unroll
    for (int r = 0; r < 16; ++r) {
        const int rl = (r & 3) + 8 * (r >> 2) + 4 * half;
        const float inv = 1.f / alf[w][rl];
        float* orow = out + ((size_t)(wq0 + rl) * NH + h) * HD;
        orow[ln]      = o0[r] * inv;
        orow[32 + ln] = o1[r] * inv;
        orow[64 + ln] = o2[r] * inv;
        orow[96 + ln] = o3[r] * inv;
    }
}

extern "C" void kernel_launch(void* const* d_in, const int* in_sizes, int n_in,
                              void* d_out, int out_size, void* d_ws, size_t ws_size,
                              hipStream_t stream) {
    const float* q = (const float*)d_in[0];
    const float* k = (const float*)d_in[1];
    const float* v = (const float*)d_in[2];
    float* out = (float*)d_out;
    if (ws_size >= (size_t)WS_NEED) {
        unsigned short* kws = (unsigned short*)d_ws;
        unsigned short* vws = kws + KB_ELEMS;
        cvt_kv3<<<256, 256, 0, stream>>>(k, v, kws, vws);
        attn_fwd12<<<256, 512, 0, stream>>>(q, kws, vws, out);
    } else {
        attn_fwd_fb<<<dim3(SEQ / BQ, NH), 256, 0, stream>>>(q, k, v, out);
    }
}